// Round 7
// baseline (305.187 us; speedup 1.0000x reference)
//
#include <hip/hip_runtime.h>
#include <stdint.h>
#include <math.h>

#define NROWS 8192
#define BHALF 4096
#define DIM 512
#define NBLK 64            // 8192/128 row-blocks
#define NTRI 2080          // 64*65/2 upper-triangle blocks (= 8 XCDs * 260)
#define NRIDER 64          // colstats rider blocks (blockIdx < 64)
#define NTOT (NTRI + NRIDER)
#define ZWORDS 26128       // sumexp 8192 + amax 16384 + col* 1536 + done/pad 16

typedef __attribute__((ext_vector_type(8))) _Float16 f16x8;
typedef __attribute__((ext_vector_type(4))) float f32x4;

__device__ __forceinline__ void gload_lds16(const void* g, void* l) {
  __builtin_amdgcn_global_load_lds(
      (const __attribute__((address_space(1))) unsigned int*)g,
      (__attribute__((address_space(3))) unsigned int*)l, 16, 0, 0);
}

// ---------------- fused prep: norms, fp16 convert, partials, zero-init ----------------
extern "C" __global__ __launch_bounds__(256) void k_prep(
    const float* __restrict__ za, const float* __restrict__ zp,
    unsigned short* __restrict__ zf,
    float* __restrict__ inv_norms, float* __restrict__ partials,
    uint32_t* __restrict__ zbase32)
{
  // zero the accumulator region (consumed only by k_gemm, a later dispatch)
  {
    int idx = blockIdx.x * 26 + threadIdx.x;
    if (threadIdx.x < 26 && idx < ZWORDS) zbase32[idx] = 0u;
  }
  __shared__ float tr_sh[4], pd_sh[4];
  const int wid = threadIdx.x >> 6, lane = threadIdx.x & 63;
  const int i = blockIdx.x * 4 + wid;                 // pair index in [0,4096)
  const float4* a4 = (const float4*)(za + (size_t)i * DIM);
  const float4* p4 = (const float4*)(zp + (size_t)i * DIM);
  float4 a0 = a4[lane * 2], a1 = a4[lane * 2 + 1];
  float4 p0 = p4[lane * 2], p1 = p4[lane * 2 + 1];
  float xa[8] = {a0.x, a0.y, a0.z, a0.w, a1.x, a1.y, a1.z, a1.w};
  float xp[8] = {p0.x, p0.y, p0.z, p0.w, p1.x, p1.y, p1.z, p1.w};
  float ssa = 0.f, ssp = 0.f;
#pragma unroll
  for (int j = 0; j < 8; ++j) { ssa += xa[j] * xa[j]; ssp += xp[j] * xp[j]; }
#pragma unroll
  for (int m = 1; m < 64; m <<= 1) {
    ssa += __shfl_xor(ssa, m, 64);
    ssp += __shfl_xor(ssp, m, 64);
  }
  float na = fmaxf(sqrtf(ssa), 1e-8f), np_ = fmaxf(sqrtf(ssp), 1e-8f);
  float ia = 1.0f / na, ip = 1.0f / np_;
  float pd = 0.f;
  unsigned short ua[8], up[8];
#pragma unroll
  for (int j = 0; j < 8; ++j) {
    float zna = xa[j] * ia, znp = xp[j] * ip;
    pd += zna * znp;
    _Float16 hza = (_Float16)zna, hzp = (_Float16)znp;   // RNE
    ua[j] = __builtin_bit_cast(unsigned short, hza);
    up[j] = __builtin_bit_cast(unsigned short, hzp);
  }
#pragma unroll
  for (int m = 1; m < 64; m <<= 1) pd += __shfl_xor(pd, m, 64);
  float tr = ssa * ia * ia + ssp * ip * ip;
  if (lane == 0) {
    tr_sh[wid] = tr; pd_sh[wid] = pd;
    inv_norms[i] = ia; inv_norms[i + BHALF] = ip;
  }
  uint4 va = {(uint32_t)ua[0] | ((uint32_t)ua[1] << 16), (uint32_t)ua[2] | ((uint32_t)ua[3] << 16),
              (uint32_t)ua[4] | ((uint32_t)ua[5] << 16), (uint32_t)ua[6] | ((uint32_t)ua[7] << 16)};
  uint4 vp = {(uint32_t)up[0] | ((uint32_t)up[1] << 16), (uint32_t)up[2] | ((uint32_t)up[3] << 16),
              (uint32_t)up[4] | ((uint32_t)up[5] << 16), (uint32_t)up[6] | ((uint32_t)up[7] << 16)};
  ((uint4*)(zf + (size_t)i * DIM))[lane] = va;
  ((uint4*)(zf + (size_t)(i + BHALF) * DIM))[lane] = vp;
  __syncthreads();
  if (threadIdx.x == 0) {
    partials[blockIdx.x * 2]     = tr_sh[0] + tr_sh[1] + tr_sh[2] + tr_sh[3];
    partials[blockIdx.x * 2 + 1] = pd_sh[0] + pd_sh[1] + pd_sh[2] + pd_sh[3];
  }
}

// ---------------- main fused kernel: riders + 128^2 fp16 pipelined GEMM + finisher ----------------
extern "C" __global__ __launch_bounds__(256) void k_gemm(
    const unsigned short* __restrict__ zf,
    const float* __restrict__ za, const float* __restrict__ zp,
    const float* __restrict__ inv_norms,
    float* __restrict__ sumexp, unsigned long long* __restrict__ amax,
    float* __restrict__ colsum, float* __restrict__ colsumsq,
    float* __restrict__ snorm, const float* __restrict__ partials,
    uint32_t* __restrict__ done, float* __restrict__ out)
{
  // double buffer: 2 x [A 16K][B 16K]; panel [128][64] fp16, slot-XOR swizzled
  __shared__ char lds[2 * 32768] __attribute__((aligned(128)));
  __shared__ uint32_t rank_sh;

  if (blockIdx.x < NRIDER) {
    // ---- rider blocks: column stats ----
    const int c = threadIdx.x;
    const int r0 = blockIdx.x * 128;
    const float* src = (r0 < BHALF) ? (za + (size_t)r0 * DIM)
                                    : (zp + (size_t)(r0 - BHALF) * DIM);
    float s0 = 0.f, q0 = 0.f, n0 = 0.f, s1 = 0.f, q1 = 0.f, n1 = 0.f;
#pragma unroll 4
    for (int rr = 0; rr < 128; ++rr) {
      float v0 = src[(size_t)rr * DIM + c];
      float v1 = src[(size_t)rr * DIM + c + 256];
      float inv = inv_norms[r0 + rr];
      s0 += v0; q0 += v0 * v0; n0 += v0 * inv;
      s1 += v1; q1 += v1 * v1; n1 += v1 * inv;
    }
    atomicAdd(&colsum[c], s0);      atomicAdd(&colsum[c + 256], s1);
    atomicAdd(&colsumsq[c], q0);    atomicAdd(&colsumsq[c + 256], q1);
    atomicAdd(&snorm[c], n0);       atomicAdd(&snorm[c + 256], n1);
  } else {
    // ---- GEMM blocks ----
    const int tid = threadIdx.x;
    const int wid = tid >> 6, lane = tid & 63;
    const int wr = wid >> 1, wc = wid & 1;
    const int fr = lane & 15, s0l = lane >> 4, fq = lane >> 4;

    // XCD-chunked column-major triangle
    const int raw = blockIdx.x - NRIDER;               // 0..2079
    const int t = (raw & 7) * 260 + (raw >> 3);
    int bj = (int)((sqrtf(8.0f * (float)t + 1.0f) - 1.0f) * 0.5f);
    while (bj < NBLK - 1 && (bj + 1) * (bj + 2) / 2 <= t) ++bj;
    while (bj > 0 && bj * (bj + 1) / 2 > t) --bj;
    const int bi = t - bj * (bj + 1) / 2;
    const int rowA = bi * 128, rowB = bj * 128;

    // staging source offsets (8 chunks of 1KB per wave, 32/buffer)
    uint32_t goff[8];
#pragma unroll
    for (int s = 0; s < 8; ++s) {
      int c = wid * 8 + s;                       // 0..31
      int p = c >> 4;                            // 0=A, 1=B
      int off = (c & 15) * 1024 + lane * 16;     // physical byte in 16KB panel
      int r = off >> 7;                          // row 0..127
      int sl = ((off >> 4) & 7) ^ (r & 7);       // logical 16B slot
      int Lb = (sl << 4) | (off & 15);
      uint32_t grow = (uint32_t)((p ? rowB : rowA) + r);
      goff[s] = grow * (uint32_t)DIM + (uint32_t)(Lb >> 1);
    }

    // fragment read offsets
    const int x = fr & 7;
    const int slk0 = ((s0l) ^ x) << 4;
    const int slk1 = ((4 + s0l) ^ x) << 4;
    const int abase = (wr * 64 + fr) * 128;
    const int bbase = 16384 + (wc * 64 + fr) * 128;

    f32x4 acc[4][4];
#pragma unroll
    for (int m = 0; m < 4; ++m)
#pragma unroll
      for (int n = 0; n < 4; ++n) acc[m][n] = (f32x4){0.f, 0.f, 0.f, 0.f};

#define STAGE(BUF, KT) do {                                                \
    char* D_ = (char*)lds + (BUF) * 32768;                                 \
    _Pragma("unroll") for (int s_ = 0; s_ < 8; ++s_) {                     \
      int c_ = wid * 8 + s_;                                               \
      gload_lds16(zf + goff[s_] + (KT) * 64,                               \
                  D_ + (c_ >> 4) * 16384 + (c_ & 15) * 1024);              \
    }                                                                      \
  } while (0)

    // prologue: stage K-step 0 into buf 0
    STAGE(0, 0);

    // main loop: ONE barrier per K-step; prefetch in flight under MFMA
#pragma unroll 2
    for (int kt = 0; kt < 8; ++kt) {
      const int buf = kt & 1;
      asm volatile("s_waitcnt lgkmcnt(0)" ::: "memory");  // my reads of buf^1 done
      asm volatile("s_waitcnt vmcnt(0)" ::: "memory");    // my stage(kt) landed
      __builtin_amdgcn_sched_barrier(0);
      __builtin_amdgcn_s_barrier();                       // everyone: same
      __builtin_amdgcn_sched_barrier(0);
      if (kt < 7) STAGE(buf ^ 1, kt + 1);                 // in flight under MFMA
      const char* Lb = (const char*)lds + buf * 32768;
      f16x8 a0[4], b0[4], a1[4], b1[4];
#pragma unroll
      for (int m = 0; m < 4; ++m) {
        a0[m] = *(const f16x8*)(Lb + abase + m * 2048 + slk0);
        a1[m] = *(const f16x8*)(Lb + abase + m * 2048 + slk1);
      }
#pragma unroll
      for (int n = 0; n < 4; ++n) {
        b0[n] = *(const f16x8*)(Lb + bbase + n * 2048 + slk0);
        b1[n] = *(const f16x8*)(Lb + bbase + n * 2048 + slk1);
      }
      __builtin_amdgcn_s_setprio(1);
#pragma unroll
      for (int m = 0; m < 4; ++m)
#pragma unroll
        for (int n = 0; n < 4; ++n)
          acc[m][n] = __builtin_amdgcn_mfma_f32_16x16x32_f16(a0[m], b0[n], acc[m][n], 0, 0, 0);
#pragma unroll
      for (int m = 0; m < 4; ++m)
#pragma unroll
        for (int n = 0; n < 4; ++n)
          acc[m][n] = __builtin_amdgcn_mfma_f32_16x16x32_f16(a1[m], b1[n], acc[m][n], 0, 0, 0);
      __builtin_amdgcn_s_setprio(0);
    }
#undef STAGE

    // ---- epilogue: single exp pass, shared row/col partials ----
    const bool isdiag = (bi == bj);
    float rse[4][4], rv[4][4]; int ri[4][4];
    float cse[4], cv[4]; int ci[4];
#pragma unroll
    for (int n = 0; n < 4; ++n) { cse[n] = 0.f; cv[n] = -INFINITY; ci[n] = 0; }
#pragma unroll
    for (int m = 0; m < 4; ++m)
#pragma unroll
      for (int rr = 0; rr < 4; ++rr) { rse[m][rr] = 0.f; rv[m][rr] = -INFINITY; ri[m][rr] = 0; }

#pragma unroll
    for (int m = 0; m < 4; ++m) {
#pragma unroll
      for (int rr = 0; rr < 4; ++rr) {
        const int gi = rowA + wr * 64 + m * 16 + fq * 4 + rr;
#pragma unroll
        for (int n = 0; n < 4; ++n) {
          const int gj = rowB + wc * 64 + n * 16 + fr;
          float lg = 2.0f * acc[m][n][rr];        // /T with T=0.5
          if (isdiag && gi == gj) lg = -INFINITY;
          float e = __expf(lg);
          rse[m][rr] += e;
          cse[n] += e;
          if (lg > rv[m][rr]) { rv[m][rr] = lg; ri[m][rr] = gj; }
          if (lg > cv[n])     { cv[n] = lg;     ci[n] = gi; }
        }
      }
    }

    // row-side reduce over fr lanes (masks 1,2,4,8)
#pragma unroll
    for (int m = 0; m < 4; ++m) {
#pragma unroll
      for (int rr = 0; rr < 4; ++rr) {
        float se = rse[m][rr], v = rv[m][rr]; int idx = ri[m][rr];
#pragma unroll
        for (int msk = 1; msk < 16; msk <<= 1) {
          float ose = __shfl_xor(se, msk, 64);
          float ov  = __shfl_xor(v, msk, 64);
          int   oi  = __shfl_xor(idx, msk, 64);
          se += ose;
          if (ov > v || (ov == v && oi < idx)) { v = ov; idx = oi; }
        }
        if (fr == 0) {
          const int gi = rowA + wr * 64 + m * 16 + fq * 4 + rr;
          uint32_t bu = __float_as_uint(v);
          uint32_t key = bu ^ ((uint32_t)((int32_t)bu >> 31) | 0x80000000u);
          unsigned long long pk = ((unsigned long long)key << 32) | (uint32_t)(~(uint32_t)idx);
          atomicAdd(&sumexp[gi], se);
          atomicMax(&amax[gi], pk);
        }
      }
    }

    // col-side reduce over fq lanes (masks 16,32), off-diagonal only
    if (!isdiag) {
#pragma unroll
      for (int n = 0; n < 4; ++n) {
        float se = cse[n], v = cv[n]; int idx = ci[n];
#pragma unroll
        for (int msk = 16; msk < 64; msk <<= 1) {
          float ose = __shfl_xor(se, msk, 64);
          float ov  = __shfl_xor(v, msk, 64);
          int   oi  = __shfl_xor(idx, msk, 64);
          se += ose;
          if (ov > v || (ov == v && oi < idx)) { v = ov; idx = oi; }
        }
        if (fq == 0) {
          const int gj = rowB + wc * 64 + n * 16 + fr;
          uint32_t bu = __float_as_uint(v);
          uint32_t key = bu ^ ((uint32_t)((int32_t)bu >> 31) | 0x80000000u);
          unsigned long long pk = ((unsigned long long)key << 32) | (uint32_t)(~(uint32_t)idx);
          atomicAdd(&sumexp[gj], se);
          atomicMax(&amax[gj], pk);
        }
      }
    }
  }

  // ---- completion counter + fused finisher (last of NTOT blocks) ----
  __threadfence();
  if (threadIdx.x == 0) rank_sh = atomicAdd(done, 1u);
  __syncthreads();
  if (rank_sh == NTOT - 1) {
    __threadfence();
    double* red = (double*)lds;
    const int t = threadIdx.x;
    double lsesum = 0.0, cnt = 0.0;
    for (int r = t; r < NROWS; r += 256) {
      lsesum += log((double)sumexp[r]);
      int label = (r < BHALF) ? r + BHALF : r - BHALF;
      unsigned int idx = ~(unsigned int)(amax[r] & 0xffffffffull);
      if ((int)idx == label) cnt += 1.0;
    }
    double stdsum = 0, mn2 = 0, sn2 = 0;
    for (int c = t; c < DIM; c += 256) {
      double su = colsum[c], sq = colsumsq[c];
      double var = (sq - su * su / 8192.0) / 8191.0;
      stdsum += sqrt(var > 0.0 ? var : 0.0);
      double m = su / 8192.0; mn2 += m * m;
      double s = snorm[c];   sn2 += s * s;
    }
    double trp = 0.0, pdp = 0.0;
    for (int b = t; b < 1024; b += 256) {
      trp += partials[b * 2];
      pdp += partials[b * 2 + 1];
    }
    auto red_sum = [&](double v) -> double {
      __syncthreads();
      red[t] = v; __syncthreads();
      for (int s = 128; s > 0; s >>= 1) {
        if (t < s) red[t] += red[t + s];
        __syncthreads();
      }
      return red[0];
    };
    double Tlse = red_sum(lsesum);
    double Tcnt = red_sum(cnt);
    double Tstd = red_sum(stdsum);
    double Tmn2 = red_sum(mn2);
    double Tsn2 = red_sum(sn2);
    double Ttr  = red_sum(trp);
    double Tpd  = red_sum(pdp);
    if (t == 0) {
      double pos_sim = Tpd / 4096.0;
      out[0] = (float)(Tlse / 8192.0 - 2.0 * pos_sim);
      out[1] = (float)(Tcnt / 8192.0);
      out[2] = (float)pos_sim;
      out[3] = (float)((Tsn2 - Ttr) / (8192.0 * 8191.0));
      out[4] = (float)(Tstd / 512.0);
      out[5] = (float)sqrt(Tmn2);
    }
  }
}

extern "C" void kernel_launch(void* const* d_in, const int* in_sizes, int n_in,
                              void* d_out, int out_size, void* d_ws, size_t ws_size,
                              hipStream_t stream) {
  const float* za = (const float*)d_in[0];
  const float* zp = (const float*)d_in[1];
  float* out = (float*)d_out;
  char* ws = (char*)d_ws;
  size_t off = 0;
  unsigned short* zf = (unsigned short*)(ws + off); off += (size_t)NROWS * DIM * 2;
  float* inv_norms = (float*)(ws + off); off += (size_t)NROWS * 4;
  char* zbase = ws + off;                              // zero-init'd by k_prep
  float* sumexp = (float*)(ws + off); off += (size_t)NROWS * 4;
  unsigned long long* amax = (unsigned long long*)(ws + off); off += (size_t)NROWS * 8;
  float* colsum = (float*)(ws + off); off += (size_t)DIM * 4;
  float* colsumsq = (float*)(ws + off); off += (size_t)DIM * 4;
  float* snorm = (float*)(ws + off); off += (size_t)DIM * 4;
  uint32_t* done = (uint32_t*)(ws + off); off += 64;   // 16 words incl. pad
  float* partials = (float*)(ws + off); off += 2048 * 4;

  k_prep<<<dim3(1024), dim3(256), 0, stream>>>(za, zp, zf, inv_norms,
                                               partials, (uint32_t*)zbase);
  k_gemm<<<dim3(NTOT), dim3(256), 0, stream>>>(
      zf, za, zp, inv_norms, sumexp, amax, colsum, colsumsq, snorm,
      partials, done, out);
}

// Round 8
// 278.183 us; speedup vs baseline: 1.0971x; 1.0971x over previous
//
#include <hip/hip_runtime.h>
#include <stdint.h>
#include <math.h>

#define NROWS 8192
#define BHALF 4096
#define DIM 512
#define NBLK 64            // 8192/128 row-blocks
#define NTRI 2080          // 64*65/2 upper-triangle blocks (= 8 XCDs * 260)
#define NRIDER 64          // colstats rider blocks (blockIdx < 64)
#define NTOT (NTRI + NRIDER)
#define ZWORDS 26128       // sumexp 8192 + amax 16384 + col* 1536 + done/pad 16

typedef __attribute__((ext_vector_type(8))) _Float16 f16x8;
typedef __attribute__((ext_vector_type(4))) float f32x4;

__device__ __forceinline__ void gload_lds16(const void* g, void* l) {
  __builtin_amdgcn_global_load_lds(
      (const __attribute__((address_space(1))) unsigned int*)g,
      (__attribute__((address_space(3))) unsigned int*)l, 16, 0, 0);
}

// ---------------- fused prep: norms, fp16 convert, partials, zero-init ----------------
extern "C" __global__ __launch_bounds__(256) void k_prep(
    const float* __restrict__ za, const float* __restrict__ zp,
    unsigned short* __restrict__ zf,
    float* __restrict__ inv_norms, float* __restrict__ partials,
    uint32_t* __restrict__ zbase32)
{
  // zero the accumulator region (consumed only by k_gemm, a later dispatch)
  {
    int idx = blockIdx.x * 26 + threadIdx.x;
    if (threadIdx.x < 26 && idx < ZWORDS) zbase32[idx] = 0u;
  }
  __shared__ float tr_sh[4], pd_sh[4];
  const int wid = threadIdx.x >> 6, lane = threadIdx.x & 63;
  const int i = blockIdx.x * 4 + wid;                 // pair index in [0,4096)
  const float4* a4 = (const float4*)(za + (size_t)i * DIM);
  const float4* p4 = (const float4*)(zp + (size_t)i * DIM);
  float4 a0 = a4[lane * 2], a1 = a4[lane * 2 + 1];
  float4 p0 = p4[lane * 2], p1 = p4[lane * 2 + 1];
  float xa[8] = {a0.x, a0.y, a0.z, a0.w, a1.x, a1.y, a1.z, a1.w};
  float xp[8] = {p0.x, p0.y, p0.z, p0.w, p1.x, p1.y, p1.z, p1.w};
  float ssa = 0.f, ssp = 0.f;
#pragma unroll
  for (int j = 0; j < 8; ++j) { ssa += xa[j] * xa[j]; ssp += xp[j] * xp[j]; }
#pragma unroll
  for (int m = 1; m < 64; m <<= 1) {
    ssa += __shfl_xor(ssa, m, 64);
    ssp += __shfl_xor(ssp, m, 64);
  }
  float na = fmaxf(sqrtf(ssa), 1e-8f), np_ = fmaxf(sqrtf(ssp), 1e-8f);
  float ia = 1.0f / na, ip = 1.0f / np_;
  float pd = 0.f;
  unsigned short ua[8], up[8];
#pragma unroll
  for (int j = 0; j < 8; ++j) {
    float zna = xa[j] * ia, znp = xp[j] * ip;
    pd += zna * znp;
    _Float16 hza = (_Float16)zna, hzp = (_Float16)znp;   // RNE
    ua[j] = __builtin_bit_cast(unsigned short, hza);
    up[j] = __builtin_bit_cast(unsigned short, hzp);
  }
#pragma unroll
  for (int m = 1; m < 64; m <<= 1) pd += __shfl_xor(pd, m, 64);
  float tr = ssa * ia * ia + ssp * ip * ip;
  if (lane == 0) {
    tr_sh[wid] = tr; pd_sh[wid] = pd;
    inv_norms[i] = ia; inv_norms[i + BHALF] = ip;
  }
  uint4 va = {(uint32_t)ua[0] | ((uint32_t)ua[1] << 16), (uint32_t)ua[2] | ((uint32_t)ua[3] << 16),
              (uint32_t)ua[4] | ((uint32_t)ua[5] << 16), (uint32_t)ua[6] | ((uint32_t)ua[7] << 16)};
  uint4 vp = {(uint32_t)up[0] | ((uint32_t)up[1] << 16), (uint32_t)up[2] | ((uint32_t)up[3] << 16),
              (uint32_t)up[4] | ((uint32_t)up[5] << 16), (uint32_t)up[6] | ((uint32_t)up[7] << 16)};
  ((uint4*)(zf + (size_t)i * DIM))[lane] = va;
  ((uint4*)(zf + (size_t)(i + BHALF) * DIM))[lane] = vp;
  __syncthreads();
  if (threadIdx.x == 0) {
    partials[blockIdx.x * 2]     = tr_sh[0] + tr_sh[1] + tr_sh[2] + tr_sh[3];
    partials[blockIdx.x * 2 + 1] = pd_sh[0] + pd_sh[1] + pd_sh[2] + pd_sh[3];
  }
}

// ---------------- main fused kernel: riders + 128^2 fp16 GEMM + fused finisher ----------------
extern "C" __global__ __launch_bounds__(256) void k_gemm(
    const unsigned short* __restrict__ zf,
    const float* __restrict__ za, const float* __restrict__ zp,
    const float* __restrict__ inv_norms,
    float* __restrict__ sumexp, unsigned long long* __restrict__ amax,
    float* __restrict__ colsum, float* __restrict__ colsumsq,
    float* __restrict__ snorm, const float* __restrict__ partials,
    uint32_t* __restrict__ done, float* __restrict__ out)
{
  // [A 16K][B 16K]; each panel [128][64] fp16 (128 B rows), slot-XOR swizzled.
  // Reused by the finisher tail (rank word + double[256] reduction scratch).
  __shared__ char lds[32768] __attribute__((aligned(128)));

  if (blockIdx.x < NRIDER) {
    // ---- rider blocks: column stats, overlapped with GEMM ----
    const int c = threadIdx.x;          // 256 threads, 2 columns each
    const int r0 = blockIdx.x * 128;
    const float* src = (r0 < BHALF) ? (za + (size_t)r0 * DIM)
                                    : (zp + (size_t)(r0 - BHALF) * DIM);
    float s0 = 0.f, q0 = 0.f, n0 = 0.f, s1 = 0.f, q1 = 0.f, n1 = 0.f;
#pragma unroll 4
    for (int rr = 0; rr < 128; ++rr) {
      float v0 = src[(size_t)rr * DIM + c];
      float v1 = src[(size_t)rr * DIM + c + 256];
      float inv = inv_norms[r0 + rr];
      s0 += v0; q0 += v0 * v0; n0 += v0 * inv;
      s1 += v1; q1 += v1 * v1; n1 += v1 * inv;
    }
    atomicAdd(&colsum[c], s0);      atomicAdd(&colsum[c + 256], s1);
    atomicAdd(&colsumsq[c], q0);    atomicAdd(&colsumsq[c + 256], q1);
    atomicAdd(&snorm[c], n0);       atomicAdd(&snorm[c + 256], n1);
  } else {
    const int tid = threadIdx.x;
    const int wid = tid >> 6, lane = tid & 63;
    const int wr = wid >> 1, wc = wid & 1;
    const int fr = lane & 15, s0l = lane >> 4, fq = lane >> 4;

    // XCD-chunked column-major triangle: XCD k (= raw%8) gets 260 consecutive t
    const int raw = blockIdx.x - NRIDER;               // 0..2079
    const int t = (raw & 7) * 260 + (raw >> 3);
    int bj = (int)((sqrtf(8.0f * (float)t + 1.0f) - 1.0f) * 0.5f);
    while (bj < NBLK - 1 && (bj + 1) * (bj + 2) / 2 <= t) ++bj;
    while (bj > 0 && bj * (bj + 1) / 2 > t) --bj;
    const int bi = t - bj * (bj + 1) / 2;
    const int rowA = bi * 128, rowB = bj * 128;

    // staging source offsets (8 chunks of 1KB per wave, 32 total)
    // panel [128][64] fp16, 128B rows = 8 slots of 16B; phys_slot = logical ^ (row&7)
    uint32_t goff[8];
#pragma unroll
    for (int s = 0; s < 8; ++s) {
      int c = wid * 8 + s;                       // 0..31
      int p = c >> 4;                            // 0=A, 1=B
      int off = (c & 15) * 1024 + lane * 16;     // physical byte in 16KB panel
      int r = off >> 7;                          // row 0..127
      int sl = ((off >> 4) & 7) ^ (r & 7);       // logical 16B slot
      int Lb = (sl << 4) | (off & 15);           // logical byte in row
      uint32_t grow = (uint32_t)((p ? rowB : rowA) + r);
      goff[s] = grow * (uint32_t)DIM + (uint32_t)(Lb >> 1);
    }

    // fragment read offsets
    const int x = fr & 7;
    const int slk0 = ((s0l) ^ x) << 4;           // ks=0: logical slot s0l
    const int slk1 = ((4 + s0l) ^ x) << 4;       // ks=1: logical slot 4+s0l
    const int abase = (wr * 64 + fr) * 128;      // + m*2048 + slk
    const int bbase = 16384 + (wc * 64 + fr) * 128;

    f32x4 acc[4][4];
#pragma unroll
    for (int m = 0; m < 4; ++m)
#pragma unroll
      for (int n = 0; n < 4; ++n) acc[m][n] = (f32x4){0.f, 0.f, 0.f, 0.f};

    // ---- main loop: 8 K-steps of BK=64, single buffer (r6-verified) ----
    for (int kt = 0; kt < 8; ++kt) {
      if (kt) __syncthreads();
#pragma unroll
      for (int s = 0; s < 8; ++s) {
        int c = wid * 8 + s;
        gload_lds16(zf + goff[s] + kt * 64,
                    (char*)lds + (c >> 4) * 16384 + (c & 15) * 1024);
      }
      __syncthreads();   // drains vmcnt + barrier: tile resident

#pragma unroll
      for (int ks = 0; ks < 2; ++ks) {
        const int slk = ks ? slk1 : slk0;
        f16x8 a[4], b[4];
#pragma unroll
        for (int m = 0; m < 4; ++m)
          a[m] = *(const f16x8*)((const char*)lds + abase + m * 2048 + slk);
#pragma unroll
        for (int n = 0; n < 4; ++n)
          b[n] = *(const f16x8*)((const char*)lds + bbase + n * 2048 + slk);
#pragma unroll
        for (int m = 0; m < 4; ++m)
#pragma unroll
          for (int n = 0; n < 4; ++n)
            acc[m][n] = __builtin_amdgcn_mfma_f32_16x16x32_f16(a[m], b[n], acc[m][n], 0, 0, 0);
      }
    }

    // ---- epilogue (r6-verified mapping) ----
    // row-side: rows gi in A-panel, reduce across 16 col-lanes (fr) + n
#pragma unroll
    for (int m = 0; m < 4; ++m) {
#pragma unroll
      for (int rr = 0; rr < 4; ++rr) {
        int gi = rowA + wr * 64 + m * 16 + fq * 4 + rr;
        float se = 0.f;
        unsigned long long best = 0ull;
#pragma unroll
        for (int n = 0; n < 4; ++n) {
          int gj = rowB + wc * 64 + n * 16 + fr;
          if (gi != gj) {
            float logit = 2.0f * acc[m][n][rr];   // /T with T=0.5
            se += __expf(logit);
            uint32_t bu = __float_as_uint(logit);
            uint32_t sk = (bu & 0x80000000u) ? ~bu : (bu | 0x80000000u);
            unsigned long long pk =
                ((unsigned long long)sk << 32) | (uint32_t)(~(uint32_t)gj);
            if (pk > best) best = pk;
          }
        }
#pragma unroll
        for (int msk = 1; msk < 16; msk <<= 1) {
          se += __shfl_xor(se, msk, 64);
          unsigned long long o = __shfl_xor(best, msk, 64);
          if (o > best) best = o;
        }
        if (fr == 0) {
          atomicAdd(&sumexp[gi], se);
          atomicMax(&amax[gi], best);
        }
      }
    }

    // col-side (off-diagonal only): rows gj in B-panel via cos^T = cos
    if (bi != bj) {
#pragma unroll
      for (int n = 0; n < 4; ++n) {
        int gj = rowB + wc * 64 + n * 16 + fr;
        float se = 0.f;
        unsigned long long best = 0ull;
#pragma unroll
        for (int m = 0; m < 4; ++m) {
#pragma unroll
          for (int rr = 0; rr < 4; ++rr) {
            int gi = rowA + wr * 64 + m * 16 + fq * 4 + rr;
            float logit = 2.0f * acc[m][n][rr];
            se += __expf(logit);
            uint32_t bu = __float_as_uint(logit);
            uint32_t sk = (bu & 0x80000000u) ? ~bu : (bu | 0x80000000u);
            unsigned long long pk =
                ((unsigned long long)sk << 32) | (uint32_t)(~(uint32_t)gi);
            if (pk > best) best = pk;
          }
        }
#pragma unroll
        for (int msk = 16; msk < 64; msk <<= 1) {
          se += __shfl_xor(se, msk, 64);
          unsigned long long o = __shfl_xor(best, msk, 64);
          if (o > best) best = o;
        }
        if (fq == 0) {
          atomicAdd(&sumexp[gj], se);
          atomicMax(&amax[gj], best);
        }
      }
    }
  }

  // ---- completion counter + fused finisher (last of NTOT blocks) ----
  __threadfence();                          // release my global writes
  __syncthreads();                          // all waves done with LDS + fences
  uint32_t* rank_sh = (uint32_t*)lds;       // reuse LDS (no extra LDS footprint)
  if (threadIdx.x == 0) *rank_sh = atomicAdd(done, 1u);
  __syncthreads();
  if (*rank_sh == NTOT - 1) {
    __threadfence();                        // acquire others' writes
    double* red = (double*)(lds + 128);
    const int t = threadIdx.x;
    double lsesum = 0.0, cnt = 0.0;
    for (int r = t; r < NROWS; r += 256) {
      lsesum += log((double)sumexp[r]);
      int label = (r < BHALF) ? r + BHALF : r - BHALF;
      unsigned int idx = ~(unsigned int)(amax[r] & 0xffffffffull);
      if ((int)idx == label) cnt += 1.0;
    }
    double stdsum = 0, mn2 = 0, sn2 = 0;
    for (int c = t; c < DIM; c += 256) {
      double su = colsum[c], sq = colsumsq[c];
      double var = (sq - su * su / 8192.0) / 8191.0;
      stdsum += sqrt(var > 0.0 ? var : 0.0);
      double m = su / 8192.0; mn2 += m * m;
      double s = snorm[c];   sn2 += s * s;
    }
    double trp = 0.0, pdp = 0.0;
    for (int b = t; b < 1024; b += 256) {
      trp += partials[b * 2];
      pdp += partials[b * 2 + 1];
    }
    auto red_sum = [&](double v) -> double {
      __syncthreads();
      red[t] = v; __syncthreads();
      for (int s = 128; s > 0; s >>= 1) {
        if (t < s) red[t] += red[t + s];
        __syncthreads();
      }
      return red[0];
    };
    double Tlse = red_sum(lsesum);
    double Tcnt = red_sum(cnt);
    double Tstd = red_sum(stdsum);
    double Tmn2 = red_sum(mn2);
    double Tsn2 = red_sum(sn2);
    double Ttr  = red_sum(trp);
    double Tpd  = red_sum(pdp);
    if (t == 0) {
      double pos_sim = Tpd / 4096.0;
      out[0] = (float)(Tlse / 8192.0 - 2.0 * pos_sim);
      out[1] = (float)(Tcnt / 8192.0);
      out[2] = (float)pos_sim;
      out[3] = (float)((Tsn2 - Ttr) / (8192.0 * 8191.0));
      out[4] = (float)(Tstd / 512.0);
      out[5] = (float)sqrt(Tmn2);
    }
  }
}

extern "C" void kernel_launch(void* const* d_in, const int* in_sizes, int n_in,
                              void* d_out, int out_size, void* d_ws, size_t ws_size,
                              hipStream_t stream) {
  const float* za = (const float*)d_in[0];
  const float* zp = (const float*)d_in[1];
  float* out = (float*)d_out;
  char* ws = (char*)d_ws;
  size_t off = 0;
  unsigned short* zf = (unsigned short*)(ws + off); off += (size_t)NROWS * DIM * 2;
  float* inv_norms = (float*)(ws + off); off += (size_t)NROWS * 4;
  char* zbase = ws + off;                              // zero-init'd by k_prep
  float* sumexp = (float*)(ws + off); off += (size_t)NROWS * 4;
  unsigned long long* amax = (unsigned long long*)(ws + off); off += (size_t)NROWS * 8;
  float* colsum = (float*)(ws + off); off += (size_t)DIM * 4;
  float* colsumsq = (float*)(ws + off); off += (size_t)DIM * 4;
  float* snorm = (float*)(ws + off); off += (size_t)DIM * 4;
  uint32_t* done = (uint32_t*)(ws + off); off += 64;   // 16 words incl. pad
  float* partials = (float*)(ws + off); off += 2048 * 4;

  k_prep<<<dim3(1024), dim3(256), 0, stream>>>(za, zp, zf, inv_norms,
                                               partials, (uint32_t*)zbase);
  k_gemm<<<dim3(NTOT), dim3(256), 0, stream>>>(
      zf, za, zp, inv_norms, sumexp, amax, colsum, colsumsq, snorm,
      partials, done, out);
}

// Round 10
// 165.620 us; speedup vs baseline: 1.8427x; 1.6796x over previous
//
#include <hip/hip_runtime.h>
#include <stdint.h>
#include <math.h>

#define NROWS 8192
#define BHALF 4096
#define DIM 512
#define NBLK 64            // 8192/128 row-blocks
#define NTRI 2080          // 64*65/2 upper-triangle blocks (= 8 XCDs * 260)
#define NRIDER 64          // colstats rider blocks (blockIdx < 64)
#define NTOT (NTRI + NRIDER)
#define ZWORDS 26128       // sumexp 8192 + amax 16384 + col* 1536 + done/pad 16

typedef __attribute__((ext_vector_type(8))) _Float16 f16x8;
typedef __attribute__((ext_vector_type(4))) float f32x4;

__device__ __forceinline__ void gload_lds16(const void* g, void* l) {
  __builtin_amdgcn_global_load_lds(
      (const __attribute__((address_space(1))) unsigned int*)g,
      (__attribute__((address_space(3))) unsigned int*)l, 16, 0, 0);
}

// ---------------- fused prep: norms, fp16 convert, partials, zero-init ----------------
extern "C" __global__ __launch_bounds__(256) void k_prep(
    const float* __restrict__ za, const float* __restrict__ zp,
    unsigned short* __restrict__ zf,
    float* __restrict__ inv_norms, float* __restrict__ partials,
    uint32_t* __restrict__ zbase32)
{
  // zero the accumulator region (consumed only by k_gemm, a later dispatch)
  {
    int idx = blockIdx.x * 26 + threadIdx.x;
    if (threadIdx.x < 26 && idx < ZWORDS) zbase32[idx] = 0u;
  }
  __shared__ float tr_sh[4], pd_sh[4];
  const int wid = threadIdx.x >> 6, lane = threadIdx.x & 63;
  const int i = blockIdx.x * 4 + wid;                 // pair index in [0,4096)
  const float4* a4 = (const float4*)(za + (size_t)i * DIM);
  const float4* p4 = (const float4*)(zp + (size_t)i * DIM);
  float4 a0 = a4[lane * 2], a1 = a4[lane * 2 + 1];
  float4 p0 = p4[lane * 2], p1 = p4[lane * 2 + 1];
  float xa[8] = {a0.x, a0.y, a0.z, a0.w, a1.x, a1.y, a1.z, a1.w};
  float xp[8] = {p0.x, p0.y, p0.z, p0.w, p1.x, p1.y, p1.z, p1.w};
  float ssa = 0.f, ssp = 0.f;
#pragma unroll
  for (int j = 0; j < 8; ++j) { ssa += xa[j] * xa[j]; ssp += xp[j] * xp[j]; }
#pragma unroll
  for (int m = 1; m < 64; m <<= 1) {
    ssa += __shfl_xor(ssa, m, 64);
    ssp += __shfl_xor(ssp, m, 64);
  }
  float na = fmaxf(sqrtf(ssa), 1e-8f), np_ = fmaxf(sqrtf(ssp), 1e-8f);
  float ia = 1.0f / na, ip = 1.0f / np_;
  float pd = 0.f;
  unsigned short ua[8], up[8];
#pragma unroll
  for (int j = 0; j < 8; ++j) {
    float zna = xa[j] * ia, znp = xp[j] * ip;
    pd += zna * znp;
    _Float16 hza = (_Float16)zna, hzp = (_Float16)znp;   // RNE
    ua[j] = __builtin_bit_cast(unsigned short, hza);
    up[j] = __builtin_bit_cast(unsigned short, hzp);
  }
#pragma unroll
  for (int m = 1; m < 64; m <<= 1) pd += __shfl_xor(pd, m, 64);
  float tr = ssa * ia * ia + ssp * ip * ip;
  if (lane == 0) {
    tr_sh[wid] = tr; pd_sh[wid] = pd;
    inv_norms[i] = ia; inv_norms[i + BHALF] = ip;
  }
  uint4 va = {(uint32_t)ua[0] | ((uint32_t)ua[1] << 16), (uint32_t)ua[2] | ((uint32_t)ua[3] << 16),
              (uint32_t)ua[4] | ((uint32_t)ua[5] << 16), (uint32_t)ua[6] | ((uint32_t)ua[7] << 16)};
  uint4 vp = {(uint32_t)up[0] | ((uint32_t)up[1] << 16), (uint32_t)up[2] | ((uint32_t)up[3] << 16),
              (uint32_t)up[4] | ((uint32_t)up[5] << 16), (uint32_t)up[6] | ((uint32_t)up[7] << 16)};
  ((uint4*)(zf + (size_t)i * DIM))[lane] = va;
  ((uint4*)(zf + (size_t)(i + BHALF) * DIM))[lane] = vp;
  __syncthreads();
  if (threadIdx.x == 0) {
    partials[blockIdx.x * 2]     = tr_sh[0] + tr_sh[1] + tr_sh[2] + tr_sh[3];
    partials[blockIdx.x * 2 + 1] = pd_sh[0] + pd_sh[1] + pd_sh[2] + pd_sh[3];
  }
}

// ---------------- main fused kernel: riders + 128^2 fp16 GEMM + fused finisher ----------------
extern "C" __global__ __launch_bounds__(256) void k_gemm(
    const unsigned short* __restrict__ zf,
    const float* __restrict__ za, const float* __restrict__ zp,
    const float* __restrict__ inv_norms,
    float* __restrict__ sumexp, unsigned long long* __restrict__ amax,
    float* __restrict__ colsum, float* __restrict__ colsumsq,
    float* __restrict__ snorm, const float* __restrict__ partials,
    uint32_t* __restrict__ done, float* __restrict__ out)
{
  // [A 16K][B 16K]; each panel [128][64] fp16 (128 B rows), slot-XOR swizzled.
  // Reused by the finisher tail (rank word + double[256] reduction scratch).
  __shared__ char lds[32768] __attribute__((aligned(128)));

  if (blockIdx.x < NRIDER) {
    // ---- rider blocks: column stats, overlapped with GEMM ----
    const int c = threadIdx.x;          // 256 threads, 2 columns each
    const int r0 = blockIdx.x * 128;
    const float* src = (r0 < BHALF) ? (za + (size_t)r0 * DIM)
                                    : (zp + (size_t)(r0 - BHALF) * DIM);
    float s0 = 0.f, q0 = 0.f, n0 = 0.f, s1 = 0.f, q1 = 0.f, n1 = 0.f;
#pragma unroll 4
    for (int rr = 0; rr < 128; ++rr) {
      float v0 = src[(size_t)rr * DIM + c];
      float v1 = src[(size_t)rr * DIM + c + 256];
      float inv = inv_norms[r0 + rr];
      s0 += v0; q0 += v0 * v0; n0 += v0 * inv;
      s1 += v1; q1 += v1 * v1; n1 += v1 * inv;
    }
    atomicAdd(&colsum[c], s0);      atomicAdd(&colsum[c + 256], s1);
    atomicAdd(&colsumsq[c], q0);    atomicAdd(&colsumsq[c + 256], q1);
    atomicAdd(&snorm[c], n0);       atomicAdd(&snorm[c + 256], n1);
  } else {
    const int tid = threadIdx.x;
    const int wid = tid >> 6, lane = tid & 63;
    const int wr = wid >> 1, wc = wid & 1;
    const int fr = lane & 15, s0l = lane >> 4, fq = lane >> 4;

    // XCD-chunked column-major triangle: XCD k (= raw%8) gets 260 consecutive t
    const int raw = blockIdx.x - NRIDER;               // 0..2079
    const int t = (raw & 7) * 260 + (raw >> 3);
    int bj = (int)((sqrtf(8.0f * (float)t + 1.0f) - 1.0f) * 0.5f);
    while (bj < NBLK - 1 && (bj + 1) * (bj + 2) / 2 <= t) ++bj;
    while (bj > 0 && bj * (bj + 1) / 2 > t) --bj;
    const int bi = t - bj * (bj + 1) / 2;
    const int rowA = bi * 128, rowB = bj * 128;

    // staging source offsets (8 chunks of 1KB per wave, 32 total)
    // panel [128][64] fp16, 128B rows = 8 slots of 16B; phys_slot = logical ^ (row&7)
    uint32_t goff[8];
#pragma unroll
    for (int s = 0; s < 8; ++s) {
      int c = wid * 8 + s;                       // 0..31
      int p = c >> 4;                            // 0=A, 1=B
      int off = (c & 15) * 1024 + lane * 16;     // physical byte in 16KB panel
      int r = off >> 7;                          // row 0..127
      int sl = ((off >> 4) & 7) ^ (r & 7);       // logical 16B slot
      int Lb = (sl << 4) | (off & 15);           // logical byte in row
      uint32_t grow = (uint32_t)((p ? rowB : rowA) + r);
      goff[s] = grow * (uint32_t)DIM + (uint32_t)(Lb >> 1);
    }

    // fragment read offsets
    const int x = fr & 7;
    const int slk0 = ((s0l) ^ x) << 4;           // ks=0: logical slot s0l
    const int slk1 = ((4 + s0l) ^ x) << 4;       // ks=1: logical slot 4+s0l
    const int abase = (wr * 64 + fr) * 128;      // + m*2048 + slk
    const int bbase = 16384 + (wc * 64 + fr) * 128;

    f32x4 acc[4][4];
#pragma unroll
    for (int m = 0; m < 4; ++m)
#pragma unroll
      for (int n = 0; n < 4; ++n) acc[m][n] = (f32x4){0.f, 0.f, 0.f, 0.f};

    // ---- main loop: 8 K-steps of BK=64, single buffer (r6-verified) ----
    for (int kt = 0; kt < 8; ++kt) {
      if (kt) __syncthreads();
#pragma unroll
      for (int s = 0; s < 8; ++s) {
        int c = wid * 8 + s;
        gload_lds16(zf + goff[s] + kt * 64,
                    (char*)lds + (c >> 4) * 16384 + (c & 15) * 1024);
      }
      __syncthreads();   // drains vmcnt + barrier: tile resident

#pragma unroll
      for (int ks = 0; ks < 2; ++ks) {
        const int slk = ks ? slk1 : slk0;
        f16x8 a[4], b[4];
#pragma unroll
        for (int m = 0; m < 4; ++m)
          a[m] = *(const f16x8*)((const char*)lds + abase + m * 2048 + slk);
#pragma unroll
        for (int n = 0; n < 4; ++n)
          b[n] = *(const f16x8*)((const char*)lds + bbase + n * 2048 + slk);
#pragma unroll
        for (int m = 0; m < 4; ++m)
#pragma unroll
          for (int n = 0; n < 4; ++n)
            acc[m][n] = __builtin_amdgcn_mfma_f32_16x16x32_f16(a[m], b[n], acc[m][n], 0, 0, 0);
      }
    }

    // ---- epilogue (r6-verified mapping) ----
    // row-side: rows gi in A-panel, reduce across 16 col-lanes (fr) + n
#pragma unroll
    for (int m = 0; m < 4; ++m) {
#pragma unroll
      for (int rr = 0; rr < 4; ++rr) {
        int gi = rowA + wr * 64 + m * 16 + fq * 4 + rr;
        float se = 0.f;
        unsigned long long best = 0ull;
#pragma unroll
        for (int n = 0; n < 4; ++n) {
          int gj = rowB + wc * 64 + n * 16 + fr;
          if (gi != gj) {
            float logit = 2.0f * acc[m][n][rr];   // /T with T=0.5
            se += __expf(logit);
            uint32_t bu = __float_as_uint(logit);
            uint32_t sk = (bu & 0x80000000u) ? ~bu : (bu | 0x80000000u);
            unsigned long long pk =
                ((unsigned long long)sk << 32) | (uint32_t)(~(uint32_t)gj);
            if (pk > best) best = pk;
          }
        }
#pragma unroll
        for (int msk = 1; msk < 16; msk <<= 1) {
          se += __shfl_xor(se, msk, 64);
          unsigned long long o = __shfl_xor(best, msk, 64);
          if (o > best) best = o;
        }
        if (fr == 0) {
          atomicAdd(&sumexp[gi], se);
          atomicMax(&amax[gi], best);
        }
      }
    }

    // col-side (off-diagonal only): rows gj in B-panel via cos^T = cos
    if (bi != bj) {
#pragma unroll
      for (int n = 0; n < 4; ++n) {
        int gj = rowB + wc * 64 + n * 16 + fr;
        float se = 0.f;
        unsigned long long best = 0ull;
#pragma unroll
        for (int m = 0; m < 4; ++m) {
#pragma unroll
          for (int rr = 0; rr < 4; ++rr) {
            int gi = rowA + wr * 64 + m * 16 + fq * 4 + rr;
            float logit = 2.0f * acc[m][n][rr];
            se += __expf(logit);
            uint32_t bu = __float_as_uint(logit);
            uint32_t sk = (bu & 0x80000000u) ? ~bu : (bu | 0x80000000u);
            unsigned long long pk =
                ((unsigned long long)sk << 32) | (uint32_t)(~(uint32_t)gi);
            if (pk > best) best = pk;
          }
        }
#pragma unroll
        for (int msk = 16; msk < 64; msk <<= 1) {
          se += __shfl_xor(se, msk, 64);
          unsigned long long o = __shfl_xor(best, msk, 64);
          if (o > best) best = o;
        }
        if (fq == 0) {
          atomicAdd(&sumexp[gj], se);
          atomicMax(&amax[gj], best);
        }
      }
    }
  }

  // ---- completion counter + fused finisher (last of NTOT blocks) ----
  // Release: our writes are ALL device-scope atomics (coherent-point RMWs);
  // per-wave vmcnt(0) drain (NO cache-maintenance fence: r8 showed per-block
  // __threadfence() L2-invalidates cost 3x on co-resident blocks).
  asm volatile("s_waitcnt vmcnt(0)" ::: "memory");
  __syncthreads();                          // all waves acked + done with LDS
  uint32_t* rank_sh = (uint32_t*)lds;       // reuse LDS (no extra footprint)
  if (threadIdx.x == 0) *rank_sh = atomicAdd(done, 1u);
  __syncthreads();
  if (*rank_sh == NTOT - 1) {
    __threadfence();                        // acquire (ONE block only): drop stale lines
    double* red = (double*)(lds + 128);
    const int t = threadIdx.x;
    double lsesum = 0.0, cnt = 0.0;
    for (int r = t; r < NROWS; r += 256) {
      lsesum += log((double)sumexp[r]);
      int label = (r < BHALF) ? r + BHALF : r - BHALF;
      unsigned int idx = ~(unsigned int)(amax[r] & 0xffffffffull);
      if ((int)idx == label) cnt += 1.0;
    }
    double stdsum = 0, mn2 = 0, sn2 = 0;
    for (int c = t; c < DIM; c += 256) {
      double su = colsum[c], sq = colsumsq[c];
      double var = (sq - su * su / 8192.0) / 8191.0;
      stdsum += sqrt(var > 0.0 ? var : 0.0);
      double m = su / 8192.0; mn2 += m * m;
      double s = snorm[c];   sn2 += s * s;
    }
    double trp = 0.0, pdp = 0.0;
    for (int b = t; b < 1024; b += 256) {
      trp += partials[b * 2];
      pdp += partials[b * 2 + 1];
    }
    auto red_sum = [&](double v) -> double {
      __syncthreads();
      red[t] = v; __syncthreads();
      for (int s = 128; s > 0; s >>= 1) {
        if (t < s) red[t] += red[t + s];
        __syncthreads();
      }
      return red[0];
    };
    double Tlse = red_sum(lsesum);
    double Tcnt = red_sum(cnt);
    double Tstd = red_sum(stdsum);
    double Tmn2 = red_sum(mn2);
    double Tsn2 = red_sum(sn2);
    double Ttr  = red_sum(trp);
    double Tpd  = red_sum(pdp);
    if (t == 0) {
      double pos_sim = Tpd / 4096.0;
      out[0] = (float)(Tlse / 8192.0 - 2.0 * pos_sim);
      out[1] = (float)(Tcnt / 8192.0);
      out[2] = (float)pos_sim;
      out[3] = (float)((Tsn2 - Ttr) / (8192.0 * 8191.0));
      out[4] = (float)(Tstd / 512.0);
      out[5] = (float)sqrt(Tmn2);
    }
  }
}

extern "C" void kernel_launch(void* const* d_in, const int* in_sizes, int n_in,
                              void* d_out, int out_size, void* d_ws, size_t ws_size,
                              hipStream_t stream) {
  const float* za = (const float*)d_in[0];
  const float* zp = (const float*)d_in[1];
  float* out = (float*)d_out;
  char* ws = (char*)d_ws;
  size_t off = 0;
  unsigned short* zf = (unsigned short*)(ws + off); off += (size_t)NROWS * DIM * 2;
  float* inv_norms = (float*)(ws + off); off += (size_t)NROWS * 4;
  char* zbase = ws + off;                              // zero-init'd by k_prep
  float* sumexp = (float*)(ws + off); off += (size_t)NROWS * 4;
  unsigned long long* amax = (unsigned long long*)(ws + off); off += (size_t)NROWS * 8;
  float* colsum = (float*)(ws + off); off += (size_t)DIM * 4;
  float* colsumsq = (float*)(ws + off); off += (size_t)DIM * 4;
  float* snorm = (float*)(ws + off); off += (size_t)DIM * 4;
  uint32_t* done = (uint32_t*)(ws + off); off += 64;   // 16 words incl. pad
  float* partials = (float*)(ws + off); off += 2048 * 4;

  k_prep<<<dim3(1024), dim3(256), 0, stream>>>(za, zp, zf, inv_norms,
                                               partials, (uint32_t*)zbase);
  k_gemm<<<dim3(NTOT), dim3(256), 0, stream>>>(
      zf, za, zp, inv_norms, sumexp, amax, colsum, colsumsq, snorm,
      partials, done, out);
}